// Round 8
// baseline (177.286 us; speedup 1.0000x reference)
//
#include <hip/hip_runtime.h>
#include <math.h>

#define N_NODES 50000
#define D_IN    128
#define E_EDGES 800000
#define H_HEADS 8
#define F_FEAT  32
#define T_TYPES 8
#define HF      256
#define NEG_SLOPE 0.2f
#define HIST_BLOCKS 256
#define GEMM_BLOCKS 208
#define OFF_BLOCKS  196          // ceil(50001/256)
#define K1_HIST_BASE GEMM_BLOCKS
#define K1_OFF_BASE  (GEMM_BLOCKS + HIST_BLOCKS)
#define K1_GRID      (GEMM_BLOCKS + HIST_BLOCKS + OFF_BLOCKS)
#define NGROUPS      ((N_NODES + 63) / 64)

using short8 = __attribute__((__ext_vector_type__(8))) short;
using f32x4  = __attribute__((__ext_vector_type__(4))) float;

__device__ inline float bf2f(unsigned short u) {
    union { unsigned int i; float f; } v; v.i = ((unsigned int)u) << 16; return v.f;
}
__device__ inline unsigned short f2bf(float f) {
    unsigned int x = __float_as_uint(f);
    unsigned int r = (x + 0x7fffu + ((x >> 16) & 1u)) >> 16;
    return (unsigned short)r;
}
__device__ inline unsigned int pk2bf(float a, float b) {
    return (unsigned int)f2bf(a) | ((unsigned int)f2bf(b) << 16);
}

// ---------------------------------------------------------------------------
// Kernel 1 (fused): blocks [0,208) MFMA node transform (persistent, W staged
// once per block); [208,464) edge-type histogram partials; [464,660) CSR
// offsets from sorted dst. The three parts are mutually independent.
// ---------------------------------------------------------------------------
__global__ __launch_bounds__(256) void prep_kernel(const float* __restrict__ feat,
                                                   const float* __restrict__ W,
                                                   const float* __restrict__ attn_l,
                                                   const float* __restrict__ attn_r,
                                                   const int*   __restrict__ etype,
                                                   const int*   __restrict__ dst,
                                                   unsigned short* __restrict__ fsb,
                                                   float* __restrict__ el,
                                                   float* __restrict__ er,
                                                   int* __restrict__ partials,
                                                   int* __restrict__ off) {
    __shared__ unsigned short Wl[HF * D_IN];   // 64 KB bf16, swizzled
    __shared__ int sw[4][8];
    const int t = threadIdx.x;

    if (blockIdx.x >= K1_OFF_BASE) {           // ---- CSR offsets part ----
        int n = (blockIdx.x - K1_OFF_BASE) * 256 + t;
        if (n > N_NODES) return;
        int lo = 0, hi = E_EDGES;
        while (lo < hi) {
            int mid = (lo + hi) >> 1;
            if (dst[mid] < n) lo = mid + 1; else hi = mid;
        }
        off[n] = lo;
        return;
    }
    if (blockIdx.x >= K1_HIST_BASE) {          // ---- histogram part ----
        const int hb = blockIdx.x - K1_HIST_BASE;
        int c[8] = {0,0,0,0,0,0,0,0};
        const int stride = HIST_BLOCKS * 256;
        for (int e = hb * 256 + t; e < E_EDGES; e += stride) {
            int ty = etype[e];
#pragma unroll
            for (int k = 0; k < 8; ++k) c[k] += (ty == k) ? 1 : 0;
        }
#pragma unroll
        for (int k = 0; k < 8; ++k) {
            c[k] += __shfl_xor(c[k], 1);  c[k] += __shfl_xor(c[k], 2);
            c[k] += __shfl_xor(c[k], 4);  c[k] += __shfl_xor(c[k], 8);
            c[k] += __shfl_xor(c[k], 16); c[k] += __shfl_xor(c[k], 32);
        }
        const int wv = t >> 6, l = t & 63;
        if (l == 0) {
#pragma unroll
            for (int k = 0; k < 8; ++k) sw[wv][k] = c[k];
        }
        __syncthreads();
        if (t < 8) partials[hb * 8 + t] = sw[0][t] + sw[1][t] + sw[2][t] + sw[3][t];
        return;
    }

    // ---- MFMA node-transform part (persistent over node groups) ----
    for (int i = 0; i < 16; ++i) {
        int slot = i * 256 + t;
        int n = slot >> 4, k16 = slot & 15;
        const float* wp = W + (size_t)n * D_IN + k16 * 8;
        float4 w0 = *(const float4*)wp;
        float4 w1 = *(const float4*)(wp + 4);
        union { unsigned int u[4]; short8 s; } ua;
        ua.u[0] = pk2bf(w0.x, w0.y); ua.u[1] = pk2bf(w0.z, w0.w);
        ua.u[2] = pk2bf(w1.x, w1.y); ua.u[3] = pk2bf(w1.z, w1.w);
        int idx = n * D_IN + ((k16 * 8) ^ ((n & 7) << 3));
        *(short8*)&Wl[idx] = ua.s;
    }
    __syncthreads();

    const int wid = t >> 6, l = t & 63;
    const int r16 = l & 15, kq = l >> 4;
    float alv0[8], alv1[8], arv0[8], arv1[8];
#pragma unroll
    for (int h = 0; h < 8; ++h) {
        alv0[h] = attn_l[h * 32 + r16];  alv1[h] = attn_l[h * 32 + 16 + r16];
        arv0[h] = attn_r[h * 32 + r16];  arv1[h] = attn_r[h * 32 + 16 + r16];
    }

    for (int grp = blockIdx.x; grp < NGROUPS; grp += GEMM_BLOCKS) {
        const int node0 = grp * 64 + wid * 16;
        int arow = node0 + r16;
        if (arow >= N_NODES) arow = N_NODES - 1;   // clamp; stores guarded
        const float* fp = feat + (size_t)arow * D_IN + kq * 8;

        f32x4 acc[16];
#pragma unroll
        for (int i = 0; i < 16; ++i) acc[i] = (f32x4){0.f, 0.f, 0.f, 0.f};

#pragma unroll
        for (int kc = 0; kc < 4; ++kc) {
            float4 a0 = *(const float4*)(fp + kc * 32);
            float4 a1 = *(const float4*)(fp + kc * 32 + 4);
            union { unsigned int u[4]; short8 s; } ua;
            ua.u[0] = pk2bf(a0.x, a0.y); ua.u[1] = pk2bf(a0.z, a0.w);
            ua.u[2] = pk2bf(a1.x, a1.y); ua.u[3] = pk2bf(a1.z, a1.w);
            short8 af = ua.s;
#pragma unroll
            for (int nsub = 0; nsub < 16; ++nsub) {
                int n = nsub * 16 + r16;
                int idx = n * D_IN + ((kc * 32 + kq * 8) ^ ((n & 7) << 3));
                short8 bf = *(short8*)&Wl[idx];
                acc[nsub] = __builtin_amdgcn_mfma_f32_16x16x32_bf16(af, bf, acc[nsub], 0, 0, 0);
            }
        }

        const int nodeb = node0 + kq * 4;
#pragma unroll
        for (int h = 0; h < 8; ++h) {
            float ev[4], rv[4];
#pragma unroll
            for (int g = 0; g < 4; ++g) {
                ev[g] = acc[2 * h][g] * alv0[h] + acc[2 * h + 1][g] * alv1[h];
                rv[g] = acc[2 * h][g] * arv0[h] + acc[2 * h + 1][g] * arv1[h];
            }
#pragma unroll
            for (int g = 0; g < 4; ++g) {
                ev[g] += __shfl_xor(ev[g], 1); ev[g] += __shfl_xor(ev[g], 2);
                ev[g] += __shfl_xor(ev[g], 4); ev[g] += __shfl_xor(ev[g], 8);
                rv[g] += __shfl_xor(rv[g], 1); rv[g] += __shfl_xor(rv[g], 2);
                rv[g] += __shfl_xor(rv[g], 4); rv[g] += __shfl_xor(rv[g], 8);
            }
            if (r16 == 0) {
#pragma unroll
                for (int g = 0; g < 4; ++g) {
                    int nd = nodeb + g;
                    if (nd < N_NODES) {
                        el[nd * 8 + h] = ev[g];
                        er[nd * 8 + h] = rv[g];
                    }
                }
            }
        }
#pragma unroll
        for (int nsub = 0; nsub < 16; ++nsub) {
            int col = nsub * 16 + r16;
#pragma unroll
            for (int g = 0; g < 4; ++g) {
                int nd = nodeb + g;
                if (nd < N_NODES) fsb[(size_t)nd * HF + col] = f2bf(acc[nsub][g]);
            }
        }
    }
}

// ---------------------------------------------------------------------------
// Kernel 2: small precomputed tables + histogram reduce
// ---------------------------------------------------------------------------
__global__ __launch_bounds__(256) void tables_kernel(const float* __restrict__ attn_e,
                              const float* __restrict__ W_e,
                              const float* __restrict__ attn_et,
                              const float* __restrict__ W_et,
                              const float* __restrict__ type_emb,
                              const int* __restrict__ partials,
                              float* __restrict__ M, float* __restrict__ ttab,
                              float* __restrict__ w) {
    __shared__ float q[8][32];
    int t = threadIdx.x;
    {   // phase 1: q[h][f2], thread = h*32+f2, coalesced W_et reads
        int h = t >> 5, f2 = t & 31;
        float s = 0.f;
#pragma unroll 8
        for (int f = 0; f < F_FEAT; ++f)
            s += attn_et[h * 32 + f] * W_et[(h * 32 + f) * 32 + f2];
        q[h][f2] = s;
    }
    __syncthreads();
    if (t < 64) {
        int h = t >> 3, j = t & 7;
        float m = 0.f;
#pragma unroll 8
        for (int f = 0; f < F_FEAT; ++f)
            m += attn_e[h * 32 + f] * W_e[(h * 32 + f) * 8 + j];
        M[h * 8 + j] = m;
        float tt = 0.f;
#pragma unroll 8
        for (int f2 = 0; f2 < F_FEAT; ++f2)
            tt += type_emb[j * 32 + f2] * q[h][f2];
        ttab[j * 8 + h] = tt;   // [type][head]
    }
    if (t < 64) {
        int j = t & 7, chunk = t >> 3;
        int c = 0;
#pragma unroll 8
        for (int b = 0; b < HIST_BLOCKS / 8; ++b)
            c += partials[(chunk * (HIST_BLOCKS / 8) + b) * 8 + j];
        c += __shfl_xor(c, 8); c += __shfl_xor(c, 16); c += __shfl_xor(c, 32);
        if (t < 8) {
            if (c < 1) c = 1;
            w[t] = (float)E_EDGES / (8.0f * (float)c);
        }
    }
}

// ---------------------------------------------------------------------------
// Kernel 3: FUSED edge-score + softmax + aggregation. One wave per dst node.
//   Per 64-edge chunk: lane l computes all 8 head scores for edge base+l
//   (ee read coalesced — edges of a node are contiguous; el[src] is a 32B
//   gather from the L2-resident 1.6MB table), packs p=exp(...) to bf16 in a
//   per-wave LDS scratch; gather loop (named-scalar unroll-4) reads p from
//   LDS and gathers fs rows. No global pexp buffer, no separate edge kernel.
// ---------------------------------------------------------------------------
__global__ __launch_bounds__(256) void agg_kernel(const float* __restrict__ ee,
        const int* __restrict__ src, const int* __restrict__ etype,
        const unsigned short* __restrict__ fsb, const float* __restrict__ el,
        const float* __restrict__ er, const int* __restrict__ off,
        const float* __restrict__ Mt, const float* __restrict__ ttab,
        const float* __restrict__ w, const float* __restrict__ bias,
        float* __restrict__ out) {
    __shared__ float sM[64], sT[64], sw[8];
    __shared__ unsigned short plds[4][64][8];   // per-wave p scratch (4 KB)
    const int t = threadIdx.x;
    if (t < 64) { sM[t] = Mt[t]; sT[t] = ttab[t]; }
    if (t >= 64 && t < 72) sw[t - 64] = w[t - 64];
    __syncthreads();
    const int wid = t >> 6, l = t & 63;
    const int n = blockIdx.x * 4 + wid;
    if (n >= N_NODES) return;
    const int beg = off[n], end = off[n + 1];
    const int c0 = 4 * l, h = l >> 3;
    const float4 b4 = *(const float4*)&bias[c0];
    float* op = &out[(size_t)n * HF + c0];
    if (beg == end) { *(float4*)op = b4; return; }
    const float4 r0v = *(const float4*)&er[n * 8];
    const float4 r1v = *(const float4*)&er[n * 8 + 4];
    const float rv[8] = {r0v.x,r0v.y,r0v.z,r0v.w,r1v.x,r1v.y,r1v.z,r1v.w};
    unsigned short* myp = &plds[wid][0][0];
    float a0 = 0.f, a1 = 0.f, a2 = 0.f, a3 = 0.f, z = 0.f;
    for (int base = beg; base < end; base += 64) {
        const int remn = end - base;
        const int rem = remn < 64 ? remn : 64;
        int idx = base + l; if (idx >= end) idx = end - 1;
        const int sl = src[idx];
        const int ty = etype[idx];
        {   // score for edge idx, all 8 heads -> LDS (lanes >= rem: unused)
            const float* eep = &ee[(size_t)idx * 8];
            const float4 e0 = *(const float4*)eep;
            const float4 e1 = *(const float4*)(eep + 4);
            const float4 l0 = *(const float4*)&el[sl * 8];
            const float4 l1 = *(const float4*)&el[sl * 8 + 4];
            const float wt = sw[ty];
            const float lv[8] = {l0.x,l0.y,l0.z,l0.w,l1.x,l1.y,l1.z,l1.w};
            unsigned int o[4];
#pragma unroll
            for (int hp = 0; hp < 4; ++hp) {
                float p2[2];
#pragma unroll
                for (int i = 0; i < 2; ++i) {
                    int hh = hp * 2 + i;
                    float sc = lv[hh] + rv[hh] + sT[ty * 8 + hh];
                    sc += e0.x*sM[hh*8+0] + e0.y*sM[hh*8+1] + e0.z*sM[hh*8+2] + e0.w*sM[hh*8+3]
                        + e1.x*sM[hh*8+4] + e1.y*sM[hh*8+5] + e1.z*sM[hh*8+6] + e1.w*sM[hh*8+7];
                    sc *= wt;
                    sc = (sc >= 0.f) ? sc : NEG_SLOPE * sc;
                    p2[i] = __expf(sc);
                }
                o[hp] = pk2bf(p2[0], p2[1]);
            }
            *(uint4*)&myp[l * 8] = make_uint4(o[0], o[1], o[2], o[3]);
        }
        int j = 0;
        for (; j + 4 <= rem; j += 4) {
            const int s0 = __shfl(sl, j),     s1 = __shfl(sl, j + 1);
            const int s2 = __shfl(sl, j + 2), s3 = __shfl(sl, j + 3);
            const float p0 = bf2f(myp[(j    ) * 8 + h]);
            const float p1 = bf2f(myp[(j + 1) * 8 + h]);
            const float p2 = bf2f(myp[(j + 2) * 8 + h]);
            const float p3 = bf2f(myp[(j + 3) * 8 + h]);
            const ushort4 f0 = *(const ushort4*)&fsb[(size_t)s0 * HF + c0];
            const ushort4 f1 = *(const ushort4*)&fsb[(size_t)s1 * HF + c0];
            const ushort4 f2 = *(const ushort4*)&fsb[(size_t)s2 * HF + c0];
            const ushort4 f3 = *(const ushort4*)&fsb[(size_t)s3 * HF + c0];
            a0 += p0 * bf2f(f0.x); a1 += p0 * bf2f(f0.y);
            a2 += p0 * bf2f(f0.z); a3 += p0 * bf2f(f0.w); z += p0;
            a0 += p1 * bf2f(f1.x); a1 += p1 * bf2f(f1.y);
            a2 += p1 * bf2f(f1.z); a3 += p1 * bf2f(f1.w); z += p1;
            a0 += p2 * bf2f(f2.x); a1 += p2 * bf2f(f2.y);
            a2 += p2 * bf2f(f2.z); a3 += p2 * bf2f(f2.w); z += p2;
            a0 += p3 * bf2f(f3.x); a1 += p3 * bf2f(f3.y);
            a2 += p3 * bf2f(f3.z); a3 += p3 * bf2f(f3.w); z += p3;
        }
        for (; j < rem; ++j) {
            const int s0 = __shfl(sl, j);
            const float p0 = bf2f(myp[j * 8 + h]);
            const ushort4 f0 = *(const ushort4*)&fsb[(size_t)s0 * HF + c0];
            a0 += p0 * bf2f(f0.x); a1 += p0 * bf2f(f0.y);
            a2 += p0 * bf2f(f0.z); a3 += p0 * bf2f(f0.w); z += p0;
        }
    }
    const float rz = 1.f / z;
    *(float4*)op = make_float4(a0 * rz + b4.x, a1 * rz + b4.y,
                               a2 * rz + b4.z, a3 * rz + b4.w);
}

// ---------------------------------------------------------------------------
extern "C" void kernel_launch(void* const* d_in, const int* in_sizes, int n_in,
                              void* d_out, int out_size, void* d_ws, size_t ws_size,
                              hipStream_t stream) {
    const float* feat     = (const float*)d_in[0];
    const float* ee       = (const float*)d_in[1];
    const int*   src      = (const int*)d_in[2];
    const int*   dst      = (const int*)d_in[3];
    const int*   etype    = (const int*)d_in[4];
    const float* W_src    = (const float*)d_in[5];
    const float* attn_l   = (const float*)d_in[6];
    const float* attn_r   = (const float*)d_in[7];
    const float* attn_e   = (const float*)d_in[8];
    const float* W_e      = (const float*)d_in[9];
    const float* type_emb = (const float*)d_in[10];
    const float* W_et     = (const float*)d_in[11];
    const float* attn_et  = (const float*)d_in[12];
    const float* bias     = (const float*)d_in[13];
    float* out = (float*)d_out;

    char* ws = (char*)d_ws;
    size_t o = 0;
    auto alloc = [&](size_t bytes) -> void* {
        void* p = ws + o;
        o = (o + bytes + 255) & ~(size_t)255;
        return p;
    };
    unsigned short* fsb  = (unsigned short*)alloc((size_t)N_NODES * HF * 2); // 25.6 MB
    float* el    = (float*)alloc((size_t)N_NODES * 8 * 4);
    float* er    = (float*)alloc((size_t)N_NODES * 8 * 4);
    int*   off   = (int*)alloc((size_t)(N_NODES + 1) * 4);
    int*   partials = (int*)alloc((size_t)HIST_BLOCKS * 8 * 4);
    float* M     = (float*)alloc(64 * 4);
    float* ttab  = (float*)alloc(64 * 4);
    float* w     = (float*)alloc(T_TYPES * 4);

    prep_kernel<<<K1_GRID, 256, 0, stream>>>(feat, W_src, attn_l, attn_r,
                                             etype, dst, fsb, el, er,
                                             partials, off);
    tables_kernel<<<1, 256, 0, stream>>>(attn_e, W_e, attn_et, W_et, type_emb,
                                         partials, M, ttab, w);
    agg_kernel<<<(N_NODES + 3) / 4, 256, 0, stream>>>(ee, src, etype, fsb, el, er,
                                                      off, M, ttab, w, bias, out);
}

// Round 9
// 125.783 us; speedup vs baseline: 1.4095x; 1.4095x over previous
//
#include <hip/hip_runtime.h>
#include <math.h>

#define N_NODES 50000
#define D_IN    128
#define E_EDGES 800000
#define H_HEADS 8
#define F_FEAT  32
#define T_TYPES 8
#define HF      256
#define NEG_SLOPE 0.2f
#define HIST_BLOCKS 256
#define GEMM_BLOCKS 416
#define OFF_BLOCKS  196          // ceil(50001/256)
#define K1_HIST_BASE GEMM_BLOCKS
#define K1_OFF_BASE  (GEMM_BLOCKS + HIST_BLOCKS)
#define K1_GRID      (GEMM_BLOCKS + HIST_BLOCKS + OFF_BLOCKS)
#define NGROUPS      ((N_NODES + 63) / 64)

using short8 = __attribute__((__ext_vector_type__(8))) short;
using f32x4  = __attribute__((__ext_vector_type__(4))) float;

__device__ inline float bf2f(unsigned short u) {
    union { unsigned int i; float f; } v; v.i = ((unsigned int)u) << 16; return v.f;
}
__device__ inline unsigned short f2bf(float f) {
    unsigned int x = __float_as_uint(f);
    unsigned int r = (x + 0x7fffu + ((x >> 16) & 1u)) >> 16;
    return (unsigned short)r;
}
__device__ inline unsigned int pk2bf(float a, float b) {
    return (unsigned int)f2bf(a) | ((unsigned int)f2bf(b) << 16);
}

// ---------------------------------------------------------------------------
// Kernel 1 (fused): blocks [0,416) MFMA node transform (persistent, W staged
// once per block, ~2 node-groups each => 2 blocks/CU); [416,672) histogram
// partials; [672,868) CSR offsets. The three parts are independent.
// ---------------------------------------------------------------------------
__global__ __launch_bounds__(256) void prep_kernel(const float* __restrict__ feat,
                                                   const float* __restrict__ W,
                                                   const float* __restrict__ attn_l,
                                                   const float* __restrict__ attn_r,
                                                   const int*   __restrict__ etype,
                                                   const int*   __restrict__ dst,
                                                   unsigned short* __restrict__ fsb,
                                                   float* __restrict__ el,
                                                   float* __restrict__ er,
                                                   int* __restrict__ partials,
                                                   int* __restrict__ off) {
    __shared__ unsigned short Wl[HF * D_IN];   // 64 KB bf16, swizzled
    __shared__ int sw[4][8];
    const int t = threadIdx.x;

    if (blockIdx.x >= K1_OFF_BASE) {           // ---- CSR offsets part ----
        int n = (blockIdx.x - K1_OFF_BASE) * 256 + t;
        if (n > N_NODES) return;
        int lo = 0, hi = E_EDGES;
        while (lo < hi) {
            int mid = (lo + hi) >> 1;
            if (dst[mid] < n) lo = mid + 1; else hi = mid;
        }
        off[n] = lo;
        return;
    }
    if (blockIdx.x >= K1_HIST_BASE) {          // ---- histogram part ----
        const int hb = blockIdx.x - K1_HIST_BASE;
        int c[8] = {0,0,0,0,0,0,0,0};
        const int stride = HIST_BLOCKS * 256;
        for (int e = hb * 256 + t; e < E_EDGES; e += stride) {
            int ty = etype[e];
#pragma unroll
            for (int k = 0; k < 8; ++k) c[k] += (ty == k) ? 1 : 0;
        }
#pragma unroll
        for (int k = 0; k < 8; ++k) {
            c[k] += __shfl_xor(c[k], 1);  c[k] += __shfl_xor(c[k], 2);
            c[k] += __shfl_xor(c[k], 4);  c[k] += __shfl_xor(c[k], 8);
            c[k] += __shfl_xor(c[k], 16); c[k] += __shfl_xor(c[k], 32);
        }
        const int wv = t >> 6, l = t & 63;
        if (l == 0) {
#pragma unroll
            for (int k = 0; k < 8; ++k) sw[wv][k] = c[k];
        }
        __syncthreads();
        if (t < 8) partials[hb * 8 + t] = sw[0][t] + sw[1][t] + sw[2][t] + sw[3][t];
        return;
    }

    // ---- MFMA node-transform part (persistent over node groups) ----
    for (int i = 0; i < 16; ++i) {
        int slot = i * 256 + t;
        int n = slot >> 4, k16 = slot & 15;
        const float* wp = W + (size_t)n * D_IN + k16 * 8;
        float4 w0 = *(const float4*)wp;
        float4 w1 = *(const float4*)(wp + 4);
        union { unsigned int u[4]; short8 s; } ua;
        ua.u[0] = pk2bf(w0.x, w0.y); ua.u[1] = pk2bf(w0.z, w0.w);
        ua.u[2] = pk2bf(w1.x, w1.y); ua.u[3] = pk2bf(w1.z, w1.w);
        int idx = n * D_IN + ((k16 * 8) ^ ((n & 7) << 3));
        *(short8*)&Wl[idx] = ua.s;
    }
    __syncthreads();

    const int wid = t >> 6, l = t & 63;
    const int r16 = l & 15, kq = l >> 4;
    float alv0[8], alv1[8], arv0[8], arv1[8];
#pragma unroll
    for (int h = 0; h < 8; ++h) {
        alv0[h] = attn_l[h * 32 + r16];  alv1[h] = attn_l[h * 32 + 16 + r16];
        arv0[h] = attn_r[h * 32 + r16];  arv1[h] = attn_r[h * 32 + 16 + r16];
    }

    for (int grp = blockIdx.x; grp < NGROUPS; grp += GEMM_BLOCKS) {
        const int node0 = grp * 64 + wid * 16;
        int arow = node0 + r16;
        if (arow >= N_NODES) arow = N_NODES - 1;   // clamp; stores guarded
        const float* fp = feat + (size_t)arow * D_IN + kq * 8;

        f32x4 acc[16];
#pragma unroll
        for (int i = 0; i < 16; ++i) acc[i] = (f32x4){0.f, 0.f, 0.f, 0.f};

#pragma unroll
        for (int kc = 0; kc < 4; ++kc) {
            float4 a0 = *(const float4*)(fp + kc * 32);
            float4 a1 = *(const float4*)(fp + kc * 32 + 4);
            union { unsigned int u[4]; short8 s; } ua;
            ua.u[0] = pk2bf(a0.x, a0.y); ua.u[1] = pk2bf(a0.z, a0.w);
            ua.u[2] = pk2bf(a1.x, a1.y); ua.u[3] = pk2bf(a1.z, a1.w);
            short8 af = ua.s;
#pragma unroll
            for (int nsub = 0; nsub < 16; ++nsub) {
                int n = nsub * 16 + r16;
                int idx = n * D_IN + ((kc * 32 + kq * 8) ^ ((n & 7) << 3));
                short8 bf = *(short8*)&Wl[idx];
                acc[nsub] = __builtin_amdgcn_mfma_f32_16x16x32_bf16(af, bf, acc[nsub], 0, 0, 0);
            }
        }

        const int nodeb = node0 + kq * 4;
#pragma unroll
        for (int h = 0; h < 8; ++h) {
            float ev[4], rv[4];
#pragma unroll
            for (int g = 0; g < 4; ++g) {
                ev[g] = acc[2 * h][g] * alv0[h] + acc[2 * h + 1][g] * alv1[h];
                rv[g] = acc[2 * h][g] * arv0[h] + acc[2 * h + 1][g] * arv1[h];
            }
#pragma unroll
            for (int g = 0; g < 4; ++g) {
                ev[g] += __shfl_xor(ev[g], 1); ev[g] += __shfl_xor(ev[g], 2);
                ev[g] += __shfl_xor(ev[g], 4); ev[g] += __shfl_xor(ev[g], 8);
                rv[g] += __shfl_xor(rv[g], 1); rv[g] += __shfl_xor(rv[g], 2);
                rv[g] += __shfl_xor(rv[g], 4); rv[g] += __shfl_xor(rv[g], 8);
            }
            if (r16 == 0) {
#pragma unroll
                for (int g = 0; g < 4; ++g) {
                    int nd = nodeb + g;
                    if (nd < N_NODES) {
                        el[nd * 8 + h] = ev[g];
                        er[nd * 8 + h] = rv[g];
                    }
                }
            }
        }
#pragma unroll
        for (int nsub = 0; nsub < 16; ++nsub) {
            int col = nsub * 16 + r16;
#pragma unroll
            for (int g = 0; g < 4; ++g) {
                int nd = nodeb + g;
                if (nd < N_NODES) fsb[(size_t)nd * HF + col] = f2bf(acc[nsub][g]);
            }
        }
    }
}

// ---------------------------------------------------------------------------
// Kernel 2: small precomputed tables + histogram reduce
// ---------------------------------------------------------------------------
__global__ __launch_bounds__(256) void tables_kernel(const float* __restrict__ attn_e,
                              const float* __restrict__ W_e,
                              const float* __restrict__ attn_et,
                              const float* __restrict__ W_et,
                              const float* __restrict__ type_emb,
                              const int* __restrict__ partials,
                              float* __restrict__ M, float* __restrict__ ttab,
                              float* __restrict__ w) {
    __shared__ float q[8][32];
    int t = threadIdx.x;
    {   // phase 1: q[h][f2], thread = h*32+f2, coalesced W_et reads
        int h = t >> 5, f2 = t & 31;
        float s = 0.f;
#pragma unroll 8
        for (int f = 0; f < F_FEAT; ++f)
            s += attn_et[h * 32 + f] * W_et[(h * 32 + f) * 32 + f2];
        q[h][f2] = s;
    }
    __syncthreads();
    if (t < 64) {
        int h = t >> 3, j = t & 7;
        float m = 0.f;
#pragma unroll 8
        for (int f = 0; f < F_FEAT; ++f)
            m += attn_e[h * 32 + f] * W_e[(h * 32 + f) * 8 + j];
        M[h * 8 + j] = m;
        float tt = 0.f;
#pragma unroll 8
        for (int f2 = 0; f2 < F_FEAT; ++f2)
            tt += type_emb[j * 32 + f2] * q[h][f2];
        ttab[j * 8 + h] = tt;   // [type][head]
    }
    if (t < 64) {
        int j = t & 7, chunk = t >> 3;
        int c = 0;
#pragma unroll 8
        for (int b = 0; b < HIST_BLOCKS / 8; ++b)
            c += partials[(chunk * (HIST_BLOCKS / 8) + b) * 8 + j];
        c += __shfl_xor(c, 8); c += __shfl_xor(c, 16); c += __shfl_xor(c, 32);
        if (t < 8) {
            if (c < 1) c = 1;
            w[t] = (float)E_EDGES / (8.0f * (float)c);
        }
    }
}

// ---------------------------------------------------------------------------
// Kernel 3: per-edge p = exp(leakyrelu(w*(el+er+escore+tscore))), bf16 out.
// ---------------------------------------------------------------------------
__global__ __launch_bounds__(256) void edge_kernel(const float* __restrict__ ee,
        const int* __restrict__ src, const int* __restrict__ dst,
        const int* __restrict__ etype, const float* __restrict__ el,
        const float* __restrict__ er, const float* __restrict__ M,
        const float* __restrict__ ttab, const float* __restrict__ w,
        unsigned short* __restrict__ pexp) {
    __shared__ float sM[64], sT[64], sw[8];
    int t = threadIdx.x;
    if (t < 64) { sM[t] = M[t]; sT[t] = ttab[t]; }
    if (t < 8) sw[t] = w[t];
    __syncthreads();
    int e = blockIdx.x * 256 + t;
    if (e >= E_EDGES) return;
    int s = src[e], d = dst[e], ty = etype[e];
    float4 e0 = *(const float4*)&ee[(size_t)e * 8];
    float4 e1 = *(const float4*)&ee[(size_t)e * 8 + 4];
    float4 l0 = *(const float4*)&el[s * 8];
    float4 l1 = *(const float4*)&el[s * 8 + 4];
    float4 r0 = *(const float4*)&er[d * 8];
    float4 r1 = *(const float4*)&er[d * 8 + 4];
    float wt = sw[ty];
    float lv[8] = {l0.x,l0.y,l0.z,l0.w,l1.x,l1.y,l1.z,l1.w};
    float rv[8] = {r0.x,r0.y,r0.z,r0.w,r1.x,r1.y,r1.z,r1.w};
    unsigned int o[4];
#pragma unroll
    for (int hp = 0; hp < 4; ++hp) {
        float p2[2];
#pragma unroll
        for (int i = 0; i < 2; ++i) {
            int h = hp * 2 + i;
            float sc = lv[h] + rv[h] + sT[ty * 8 + h];
            sc += e0.x*sM[h*8+0] + e0.y*sM[h*8+1] + e0.z*sM[h*8+2] + e0.w*sM[h*8+3]
                + e1.x*sM[h*8+4] + e1.y*sM[h*8+5] + e1.z*sM[h*8+6] + e1.w*sM[h*8+7];
            sc *= wt;
            sc = (sc >= 0.f) ? sc : NEG_SLOPE * sc;
            p2[i] = __expf(sc);
        }
        o[hp] = (unsigned int)f2bf(p2[0]) | ((unsigned int)f2bf(p2[1]) << 16);
    }
    *(uint4*)&pexp[(size_t)e * 8] = make_uint4(o[0], o[1], o[2], o[3]);
}

// ---------------------------------------------------------------------------
// Kernel 4: single-pass softmax-normalized aggregation. One wave per dst node.
//   Cooperative src prefetch + NAMED-SCALAR 8x unroll (arrays de-register:
//   round-7/8 lesson) -> 8 independent fs-row gathers in flight per wave.
// ---------------------------------------------------------------------------
__global__ __launch_bounds__(256) void agg_kernel(const unsigned short* __restrict__ pexp,
        const unsigned short* __restrict__ fsb, const int* __restrict__ src,
        const int* __restrict__ off, const float* __restrict__ bias,
        float* __restrict__ out) {
    const int wid = threadIdx.x >> 6;
    const int l = threadIdx.x & 63;
    const int n = blockIdx.x * 4 + wid;
    if (n >= N_NODES) return;
    const int beg = off[n], end = off[n + 1];
    const int c0 = 4 * l;
    const int h = l >> 3;
    const float4 b4 = *(const float4*)&bias[c0];
    float* op = &out[(size_t)n * HF + c0];
    if (beg == end) { *(float4*)op = b4; return; }
    float a0 = 0.f, a1 = 0.f, a2 = 0.f, a3 = 0.f, z = 0.f;
    for (int base = beg; base < end; base += 64) {
        const int remn = end - base;
        const int rem = remn < 64 ? remn : 64;
        int idx = base + l; if (idx >= end) idx = end - 1;
        const int sl = src[idx];                 // one coalesced read / chunk
        int j = 0;
        for (; j + 8 <= rem; j += 8) {
            const int s0 = __shfl(sl, j),     s1 = __shfl(sl, j + 1);
            const int s2 = __shfl(sl, j + 2), s3 = __shfl(sl, j + 3);
            const int s4 = __shfl(sl, j + 4), s5 = __shfl(sl, j + 5);
            const int s6 = __shfl(sl, j + 6), s7 = __shfl(sl, j + 7);
            const float p0 = bf2f(pexp[(size_t)(base + j    ) * 8 + h]);
            const float p1 = bf2f(pexp[(size_t)(base + j + 1) * 8 + h]);
            const float p2 = bf2f(pexp[(size_t)(base + j + 2) * 8 + h]);
            const float p3 = bf2f(pexp[(size_t)(base + j + 3) * 8 + h]);
            const float p4 = bf2f(pexp[(size_t)(base + j + 4) * 8 + h]);
            const float p5 = bf2f(pexp[(size_t)(base + j + 5) * 8 + h]);
            const float p6 = bf2f(pexp[(size_t)(base + j + 6) * 8 + h]);
            const float p7 = bf2f(pexp[(size_t)(base + j + 7) * 8 + h]);
            const ushort4 f0 = *(const ushort4*)&fsb[(size_t)s0 * HF + c0];
            const ushort4 f1 = *(const ushort4*)&fsb[(size_t)s1 * HF + c0];
            const ushort4 f2 = *(const ushort4*)&fsb[(size_t)s2 * HF + c0];
            const ushort4 f3 = *(const ushort4*)&fsb[(size_t)s3 * HF + c0];
            const ushort4 f4 = *(const ushort4*)&fsb[(size_t)s4 * HF + c0];
            const ushort4 f5 = *(const ushort4*)&fsb[(size_t)s5 * HF + c0];
            const ushort4 f6 = *(const ushort4*)&fsb[(size_t)s6 * HF + c0];
            const ushort4 f7 = *(const ushort4*)&fsb[(size_t)s7 * HF + c0];
            a0 += p0 * bf2f(f0.x); a1 += p0 * bf2f(f0.y);
            a2 += p0 * bf2f(f0.z); a3 += p0 * bf2f(f0.w); z += p0;
            a0 += p1 * bf2f(f1.x); a1 += p1 * bf2f(f1.y);
            a2 += p1 * bf2f(f1.z); a3 += p1 * bf2f(f1.w); z += p1;
            a0 += p2 * bf2f(f2.x); a1 += p2 * bf2f(f2.y);
            a2 += p2 * bf2f(f2.z); a3 += p2 * bf2f(f2.w); z += p2;
            a0 += p3 * bf2f(f3.x); a1 += p3 * bf2f(f3.y);
            a2 += p3 * bf2f(f3.z); a3 += p3 * bf2f(f3.w); z += p3;
            a0 += p4 * bf2f(f4.x); a1 += p4 * bf2f(f4.y);
            a2 += p4 * bf2f(f4.z); a3 += p4 * bf2f(f4.w); z += p4;
            a0 += p5 * bf2f(f5.x); a1 += p5 * bf2f(f5.y);
            a2 += p5 * bf2f(f5.z); a3 += p5 * bf2f(f5.w); z += p5;
            a0 += p6 * bf2f(f6.x); a1 += p6 * bf2f(f6.y);
            a2 += p6 * bf2f(f6.z); a3 += p6 * bf2f(f6.w); z += p6;
            a0 += p7 * bf2f(f7.x); a1 += p7 * bf2f(f7.y);
            a2 += p7 * bf2f(f7.z); a3 += p7 * bf2f(f7.w); z += p7;
        }
        for (; j < rem; ++j) {
            const int s0 = __shfl(sl, j);
            const float p0 = bf2f(pexp[(size_t)(base + j) * 8 + h]);
            const ushort4 f0 = *(const ushort4*)&fsb[(size_t)s0 * HF + c0];
            a0 += p0 * bf2f(f0.x); a1 += p0 * bf2f(f0.y);
            a2 += p0 * bf2f(f0.z); a3 += p0 * bf2f(f0.w); z += p0;
        }
    }
    const float rz = 1.f / z;
    *(float4*)op = make_float4(a0 * rz + b4.x, a1 * rz + b4.y,
                               a2 * rz + b4.z, a3 * rz + b4.w);
}

// ---------------------------------------------------------------------------
extern "C" void kernel_launch(void* const* d_in, const int* in_sizes, int n_in,
                              void* d_out, int out_size, void* d_ws, size_t ws_size,
                              hipStream_t stream) {
    const float* feat     = (const float*)d_in[0];
    const float* ee       = (const float*)d_in[1];
    const int*   src      = (const int*)d_in[2];
    const int*   dst      = (const int*)d_in[3];
    const int*   etype    = (const int*)d_in[4];
    const float* W_src    = (const float*)d_in[5];
    const float* attn_l   = (const float*)d_in[6];
    const float* attn_r   = (const float*)d_in[7];
    const float* attn_e   = (const float*)d_in[8];
    const float* W_e      = (const float*)d_in[9];
    const float* type_emb = (const float*)d_in[10];
    const float* W_et     = (const float*)d_in[11];
    const float* attn_et  = (const float*)d_in[12];
    const float* bias     = (const float*)d_in[13];
    float* out = (float*)d_out;

    char* ws = (char*)d_ws;
    size_t o = 0;
    auto alloc = [&](size_t bytes) -> void* {
        void* p = ws + o;
        o = (o + bytes + 255) & ~(size_t)255;
        return p;
    };
    unsigned short* fsb  = (unsigned short*)alloc((size_t)N_NODES * HF * 2); // 25.6 MB
    unsigned short* pexp = (unsigned short*)alloc((size_t)E_EDGES * 8 * 2);  // 12.8 MB
    float* el    = (float*)alloc((size_t)N_NODES * 8 * 4);
    float* er    = (float*)alloc((size_t)N_NODES * 8 * 4);
    int*   off   = (int*)alloc((size_t)(N_NODES + 1) * 4);
    int*   partials = (int*)alloc((size_t)HIST_BLOCKS * 8 * 4);
    float* M     = (float*)alloc(64 * 4);
    float* ttab  = (float*)alloc(64 * 4);
    float* w     = (float*)alloc(T_TYPES * 4);

    prep_kernel<<<K1_GRID, 256, 0, stream>>>(feat, W_src, attn_l, attn_r,
                                             etype, dst, fsb, el, er,
                                             partials, off);
    tables_kernel<<<1, 256, 0, stream>>>(attn_e, W_e, attn_et, W_et, type_emb,
                                         partials, M, ttab, w);
    edge_kernel<<<(E_EDGES + 255) / 256, 256, 0, stream>>>(
        ee, src, dst, etype, el, er, M, ttab, w, pexp);
    agg_kernel<<<(N_NODES + 3) / 4, 256, 0, stream>>>(pexp, fsb, src, off, bias, out);
}

// Round 10
// 113.137 us; speedup vs baseline: 1.5670x; 1.1118x over previous
//
#include <hip/hip_runtime.h>
#include <math.h>

#define N_NODES 50000
#define D_IN    128
#define E_EDGES 800000
#define H_HEADS 8
#define F_FEAT  32
#define T_TYPES 8
#define HF      256
#define NEG_SLOPE 0.2f
#define HIST_BLOCKS 256
#define GEMM_BLOCKS 416
#define OFF_BLOCKS  196          // ceil(50001/256)
#define K1_HIST_BASE GEMM_BLOCKS
#define K1_OFF_BASE  (GEMM_BLOCKS + HIST_BLOCKS)
#define K1_GRID      (GEMM_BLOCKS + HIST_BLOCKS + OFF_BLOCKS)
#define NGROUPS      ((N_NODES + 63) / 64)

using short8 = __attribute__((__ext_vector_type__(8))) short;
using f32x4  = __attribute__((__ext_vector_type__(4))) float;

__device__ inline float bf2f(unsigned short u) {
    union { unsigned int i; float f; } v; v.i = ((unsigned int)u) << 16; return v.f;
}
__device__ inline unsigned short f2bf(float f) {
    unsigned int x = __float_as_uint(f);
    unsigned int r = (x + 0x7fffu + ((x >> 16) & 1u)) >> 16;
    return (unsigned short)r;
}
__device__ inline unsigned int pk2bf(float a, float b) {
    return (unsigned int)f2bf(a) | ((unsigned int)f2bf(b) << 16);
}

// ---------------------------------------------------------------------------
// Kernel 1 (fused): blocks [0,416) MFMA node transform (persistent, W staged
// once per block); [416,672) histogram partials; [672,868) CSR offsets.
// ---------------------------------------------------------------------------
__global__ __launch_bounds__(256) void prep_kernel(const float* __restrict__ feat,
                                                   const float* __restrict__ W,
                                                   const float* __restrict__ attn_l,
                                                   const float* __restrict__ attn_r,
                                                   const int*   __restrict__ etype,
                                                   const int*   __restrict__ dst,
                                                   unsigned short* __restrict__ fsb,
                                                   float* __restrict__ el,
                                                   float* __restrict__ er,
                                                   int* __restrict__ partials,
                                                   int* __restrict__ off) {
    __shared__ unsigned short Wl[HF * D_IN];   // 64 KB bf16, swizzled
    __shared__ int sw[4][8];
    const int t = threadIdx.x;

    if (blockIdx.x >= K1_OFF_BASE) {           // ---- CSR offsets part ----
        int n = (blockIdx.x - K1_OFF_BASE) * 256 + t;
        if (n > N_NODES) return;
        int lo = 0, hi = E_EDGES;
        while (lo < hi) {
            int mid = (lo + hi) >> 1;
            if (dst[mid] < n) lo = mid + 1; else hi = mid;
        }
        off[n] = lo;
        return;
    }
    if (blockIdx.x >= K1_HIST_BASE) {          // ---- histogram part ----
        const int hb = blockIdx.x - K1_HIST_BASE;
        int c[8] = {0,0,0,0,0,0,0,0};
        const int stride = HIST_BLOCKS * 256;
        for (int e = hb * 256 + t; e < E_EDGES; e += stride) {
            int ty = etype[e];
#pragma unroll
            for (int k = 0; k < 8; ++k) c[k] += (ty == k) ? 1 : 0;
        }
#pragma unroll
        for (int k = 0; k < 8; ++k) {
            c[k] += __shfl_xor(c[k], 1);  c[k] += __shfl_xor(c[k], 2);
            c[k] += __shfl_xor(c[k], 4);  c[k] += __shfl_xor(c[k], 8);
            c[k] += __shfl_xor(c[k], 16); c[k] += __shfl_xor(c[k], 32);
        }
        const int wv = t >> 6, l = t & 63;
        if (l == 0) {
#pragma unroll
            for (int k = 0; k < 8; ++k) sw[wv][k] = c[k];
        }
        __syncthreads();
        if (t < 8) partials[hb * 8 + t] = sw[0][t] + sw[1][t] + sw[2][t] + sw[3][t];
        return;
    }

    // ---- MFMA node-transform part (persistent over node groups) ----
    for (int i = 0; i < 16; ++i) {
        int slot = i * 256 + t;
        int n = slot >> 4, k16 = slot & 15;
        const float* wp = W + (size_t)n * D_IN + k16 * 8;
        float4 w0 = *(const float4*)wp;
        float4 w1 = *(const float4*)(wp + 4);
        union { unsigned int u[4]; short8 s; } ua;
        ua.u[0] = pk2bf(w0.x, w0.y); ua.u[1] = pk2bf(w0.z, w0.w);
        ua.u[2] = pk2bf(w1.x, w1.y); ua.u[3] = pk2bf(w1.z, w1.w);
        int idx = n * D_IN + ((k16 * 8) ^ ((n & 7) << 3));
        *(short8*)&Wl[idx] = ua.s;
    }
    __syncthreads();

    const int wid = t >> 6, l = t & 63;
    const int r16 = l & 15, kq = l >> 4;
    float alv0[8], alv1[8], arv0[8], arv1[8];
#pragma unroll
    for (int h = 0; h < 8; ++h) {
        alv0[h] = attn_l[h * 32 + r16];  alv1[h] = attn_l[h * 32 + 16 + r16];
        arv0[h] = attn_r[h * 32 + r16];  arv1[h] = attn_r[h * 32 + 16 + r16];
    }

    for (int grp = blockIdx.x; grp < NGROUPS; grp += GEMM_BLOCKS) {
        const int node0 = grp * 64 + wid * 16;
        int arow = node0 + r16;
        if (arow >= N_NODES) arow = N_NODES - 1;   // clamp; stores guarded
        const float* fp = feat + (size_t)arow * D_IN + kq * 8;

        f32x4 acc[16];
#pragma unroll
        for (int i = 0; i < 16; ++i) acc[i] = (f32x4){0.f, 0.f, 0.f, 0.f};

#pragma unroll
        for (int kc = 0; kc < 4; ++kc) {
            float4 a0 = *(const float4*)(fp + kc * 32);
            float4 a1 = *(const float4*)(fp + kc * 32 + 4);
            union { unsigned int u[4]; short8 s; } ua;
            ua.u[0] = pk2bf(a0.x, a0.y); ua.u[1] = pk2bf(a0.z, a0.w);
            ua.u[2] = pk2bf(a1.x, a1.y); ua.u[3] = pk2bf(a1.z, a1.w);
            short8 af = ua.s;
#pragma unroll
            for (int nsub = 0; nsub < 16; ++nsub) {
                int n = nsub * 16 + r16;
                int idx = n * D_IN + ((kc * 32 + kq * 8) ^ ((n & 7) << 3));
                short8 bf = *(short8*)&Wl[idx];
                acc[nsub] = __builtin_amdgcn_mfma_f32_16x16x32_bf16(af, bf, acc[nsub], 0, 0, 0);
            }
        }

        const int nodeb = node0 + kq * 4;
#pragma unroll
        for (int h = 0; h < 8; ++h) {
            float ev[4], rv[4];
#pragma unroll
            for (int g = 0; g < 4; ++g) {
                ev[g] = acc[2 * h][g] * alv0[h] + acc[2 * h + 1][g] * alv1[h];
                rv[g] = acc[2 * h][g] * arv0[h] + acc[2 * h + 1][g] * arv1[h];
            }
#pragma unroll
            for (int g = 0; g < 4; ++g) {
                ev[g] += __shfl_xor(ev[g], 1); ev[g] += __shfl_xor(ev[g], 2);
                ev[g] += __shfl_xor(ev[g], 4); ev[g] += __shfl_xor(ev[g], 8);
                rv[g] += __shfl_xor(rv[g], 1); rv[g] += __shfl_xor(rv[g], 2);
                rv[g] += __shfl_xor(rv[g], 4); rv[g] += __shfl_xor(rv[g], 8);
            }
            if (r16 == 0) {
#pragma unroll
                for (int g = 0; g < 4; ++g) {
                    int nd = nodeb + g;
                    if (nd < N_NODES) {
                        el[nd * 8 + h] = ev[g];
                        er[nd * 8 + h] = rv[g];
                    }
                }
            }
        }
#pragma unroll
        for (int nsub = 0; nsub < 16; ++nsub) {
            int col = nsub * 16 + r16;
#pragma unroll
            for (int g = 0; g < 4; ++g) {
                int nd = nodeb + g;
                if (nd < N_NODES) fsb[(size_t)nd * HF + col] = f2bf(acc[nsub][g]);
            }
        }
    }
}

// ---------------------------------------------------------------------------
// Kernel 2: small precomputed tables + histogram reduce
// ---------------------------------------------------------------------------
__global__ __launch_bounds__(256) void tables_kernel(const float* __restrict__ attn_e,
                              const float* __restrict__ W_e,
                              const float* __restrict__ attn_et,
                              const float* __restrict__ W_et,
                              const float* __restrict__ type_emb,
                              const int* __restrict__ partials,
                              float* __restrict__ M, float* __restrict__ ttab,
                              float* __restrict__ w) {
    __shared__ float q[8][32];
    int t = threadIdx.x;
    {   // phase 1: q[h][f2], thread = h*32+f2, coalesced W_et reads
        int h = t >> 5, f2 = t & 31;
        float s = 0.f;
#pragma unroll 8
        for (int f = 0; f < F_FEAT; ++f)
            s += attn_et[h * 32 + f] * W_et[(h * 32 + f) * 32 + f2];
        q[h][f2] = s;
    }
    __syncthreads();
    if (t < 64) {
        int h = t >> 3, j = t & 7;
        float m = 0.f;
#pragma unroll 8
        for (int f = 0; f < F_FEAT; ++f)
            m += attn_e[h * 32 + f] * W_e[(h * 32 + f) * 8 + j];
        M[h * 8 + j] = m;
        float tt = 0.f;
#pragma unroll 8
        for (int f2 = 0; f2 < F_FEAT; ++f2)
            tt += type_emb[j * 32 + f2] * q[h][f2];
        ttab[j * 8 + h] = tt;   // [type][head]
    }
    if (t < 64) {
        int j = t & 7, chunk = t >> 3;
        int c = 0;
#pragma unroll 8
        for (int b = 0; b < HIST_BLOCKS / 8; ++b)
            c += partials[(chunk * (HIST_BLOCKS / 8) + b) * 8 + j];
        c += __shfl_xor(c, 8); c += __shfl_xor(c, 16); c += __shfl_xor(c, 32);
        if (t < 8) {
            if (c < 1) c = 1;
            w[t] = (float)E_EDGES / (8.0f * (float)c);
        }
    }
}

// ---------------------------------------------------------------------------
// Kernel 3: per-edge p = exp(leakyrelu(w*(el+er+escore+tscore))), bf16 out.
// ---------------------------------------------------------------------------
__global__ __launch_bounds__(256) void edge_kernel(const float* __restrict__ ee,
        const int* __restrict__ src, const int* __restrict__ dst,
        const int* __restrict__ etype, const float* __restrict__ el,
        const float* __restrict__ er, const float* __restrict__ M,
        const float* __restrict__ ttab, const float* __restrict__ w,
        unsigned short* __restrict__ pexp) {
    __shared__ float sM[64], sT[64], sw[8];
    int t = threadIdx.x;
    if (t < 64) { sM[t] = M[t]; sT[t] = ttab[t]; }
    if (t < 8) sw[t] = w[t];
    __syncthreads();
    int e = blockIdx.x * 256 + t;
    if (e >= E_EDGES) return;
    int s = src[e], d = dst[e], ty = etype[e];
    float4 e0 = *(const float4*)&ee[(size_t)e * 8];
    float4 e1 = *(const float4*)&ee[(size_t)e * 8 + 4];
    float4 l0 = *(const float4*)&el[s * 8];
    float4 l1 = *(const float4*)&el[s * 8 + 4];
    float4 r0 = *(const float4*)&er[d * 8];
    float4 r1 = *(const float4*)&er[d * 8 + 4];
    float wt = sw[ty];
    float lv[8] = {l0.x,l0.y,l0.z,l0.w,l1.x,l1.y,l1.z,l1.w};
    float rv[8] = {r0.x,r0.y,r0.z,r0.w,r1.x,r1.y,r1.z,r1.w};
    unsigned int o[4];
#pragma unroll
    for (int hp = 0; hp < 4; ++hp) {
        float p2[2];
#pragma unroll
        for (int i = 0; i < 2; ++i) {
            int h = hp * 2 + i;
            float sc = lv[h] + rv[h] + sT[ty * 8 + h];
            sc += e0.x*sM[h*8+0] + e0.y*sM[h*8+1] + e0.z*sM[h*8+2] + e0.w*sM[h*8+3]
                + e1.x*sM[h*8+4] + e1.y*sM[h*8+5] + e1.z*sM[h*8+6] + e1.w*sM[h*8+7];
            sc *= wt;
            sc = (sc >= 0.f) ? sc : NEG_SLOPE * sc;
            p2[i] = __expf(sc);
        }
        o[hp] = (unsigned int)f2bf(p2[0]) | ((unsigned int)f2bf(p2[1]) << 16);
    }
    *(uint4*)&pexp[(size_t)e * 8] = make_uint4(o[0], o[1], o[2], o[3]);
}

// ---------------------------------------------------------------------------
// Kernel 4: single-pass softmax-normalized aggregation. One wave per dst node.
//   Per 64-edge chunk: coalesced src read (-> shfl) + cooperative pexp-chunk
//   stage to wave-private LDS (1 KB, uint4/lane, no barrier needed). Inner
//   loop = named-scalar unroll-4 with the fs gather as the ONLY global load.
// ---------------------------------------------------------------------------
__global__ __launch_bounds__(256) void agg_kernel(const unsigned short* __restrict__ pexp,
        const unsigned short* __restrict__ fsb, const int* __restrict__ src,
        const int* __restrict__ off, const float* __restrict__ bias,
        float* __restrict__ out) {
    __shared__ unsigned short plds[4][64][8];   // wave-private p scratch (4 KB)
    const int wid = threadIdx.x >> 6;
    const int l = threadIdx.x & 63;
    const int n = blockIdx.x * 4 + wid;
    if (n >= N_NODES) return;
    const int beg = off[n], end = off[n + 1];
    const int c0 = 4 * l;
    const int h = l >> 3;
    const float4 b4 = *(const float4*)&bias[c0];
    float* op = &out[(size_t)n * HF + c0];
    if (beg == end) { *(float4*)op = b4; return; }
    const unsigned short* mp = &plds[wid][0][0];
    float a0 = 0.f, a1 = 0.f, a2 = 0.f, a3 = 0.f, z = 0.f;
    for (int base = beg; base < end; base += 64) {
        const int remn = end - base;
        const int rem = remn < 64 ? remn : 64;
        int idx = base + l; if (idx >= end) idx = end - 1;
        const int sl = src[idx];                 // coalesced
        {   // stage this chunk's pexp block (64x8 bf16 = 1KB) into LDS
            const uint4 pv = *(const uint4*)&pexp[(size_t)idx * 8];
            *(uint4*)&plds[wid][l][0] = pv;
        }
        int j = 0;
        for (; j + 4 <= rem; j += 4) {
            const int s0 = __shfl(sl, j),     s1 = __shfl(sl, j + 1);
            const int s2 = __shfl(sl, j + 2), s3 = __shfl(sl, j + 3);
            const float p0 = bf2f(mp[(j    ) * 8 + h]);
            const float p1 = bf2f(mp[(j + 1) * 8 + h]);
            const float p2 = bf2f(mp[(j + 2) * 8 + h]);
            const float p3 = bf2f(mp[(j + 3) * 8 + h]);
            const ushort4 f0 = *(const ushort4*)&fsb[(size_t)s0 * HF + c0];
            const ushort4 f1 = *(const ushort4*)&fsb[(size_t)s1 * HF + c0];
            const ushort4 f2 = *(const ushort4*)&fsb[(size_t)s2 * HF + c0];
            const ushort4 f3 = *(const ushort4*)&fsb[(size_t)s3 * HF + c0];
            a0 += p0 * bf2f(f0.x); a1 += p0 * bf2f(f0.y);
            a2 += p0 * bf2f(f0.z); a3 += p0 * bf2f(f0.w); z += p0;
            a0 += p1 * bf2f(f1.x); a1 += p1 * bf2f(f1.y);
            a2 += p1 * bf2f(f1.z); a3 += p1 * bf2f(f1.w); z += p1;
            a0 += p2 * bf2f(f2.x); a1 += p2 * bf2f(f2.y);
            a2 += p2 * bf2f(f2.z); a3 += p2 * bf2f(f2.w); z += p2;
            a0 += p3 * bf2f(f3.x); a1 += p3 * bf2f(f3.y);
            a2 += p3 * bf2f(f3.z); a3 += p3 * bf2f(f3.w); z += p3;
        }
        for (; j < rem; ++j) {
            const int s0 = __shfl(sl, j);
            const float p0 = bf2f(mp[j * 8 + h]);
            const ushort4 f0 = *(const ushort4*)&fsb[(size_t)s0 * HF + c0];
            a0 += p0 * bf2f(f0.x); a1 += p0 * bf2f(f0.y);
            a2 += p0 * bf2f(f0.z); a3 += p0 * bf2f(f0.w); z += p0;
        }
    }
    const float rz = 1.f / z;
    *(float4*)op = make_float4(a0 * rz + b4.x, a1 * rz + b4.y,
                               a2 * rz + b4.z, a3 * rz + b4.w);
}

// ---------------------------------------------------------------------------
extern "C" void kernel_launch(void* const* d_in, const int* in_sizes, int n_in,
                              void* d_out, int out_size, void* d_ws, size_t ws_size,
                              hipStream_t stream) {
    const float* feat     = (const float*)d_in[0];
    const float* ee       = (const float*)d_in[1];
    const int*   src      = (const int*)d_in[2];
    const int*   dst      = (const int*)d_in[3];
    const int*   etype    = (const int*)d_in[4];
    const float* W_src    = (const float*)d_in[5];
    const float* attn_l   = (const float*)d_in[6];
    const float* attn_r   = (const float*)d_in[7];
    const float* attn_e   = (const float*)d_in[8];
    const float* W_e      = (const float*)d_in[9];
    const float* type_emb = (const float*)d_in[10];
    const float* W_et     = (const float*)d_in[11];
    const float* attn_et  = (const float*)d_in[12];
    const float* bias     = (const float*)d_in[13];
    float* out = (float*)d_out;

    char* ws = (char*)d_ws;
    size_t o = 0;
    auto alloc = [&](size_t bytes) -> void* {
        void* p = ws + o;
        o = (o + bytes + 255) & ~(size_t)255;
        return p;
    };
    unsigned short* fsb  = (unsigned short*)alloc((size_t)N_NODES * HF * 2); // 25.6 MB
    unsigned short* pexp = (unsigned short*)alloc((size_t)E_EDGES * 8 * 2);  // 12.8 MB
    float* el    = (float*)alloc((size_t)N_NODES * 8 * 4);
    float* er    = (float*)alloc((size_t)N_NODES * 8 * 4);
    int*   off   = (int*)alloc((size_t)(N_NODES + 1) * 4);
    int*   partials = (int*)alloc((size_t)HIST_BLOCKS * 8 * 4);
    float* M     = (float*)alloc(64 * 4);
    float* ttab  = (float*)alloc(64 * 4);
    float* w     = (float*)alloc(T_TYPES * 4);

    prep_kernel<<<K1_GRID, 256, 0, stream>>>(feat, W_src, attn_l, attn_r,
                                             etype, dst, fsb, el, er,
                                             partials, off);
    tables_kernel<<<1, 256, 0, stream>>>(attn_e, W_e, attn_et, W_et, type_emb,
                                         partials, M, ttab, w);
    edge_kernel<<<(E_EDGES + 255) / 256, 256, 0, stream>>>(
        ee, src, dst, etype, el, er, M, ttab, w, pexp);
    agg_kernel<<<(N_NODES + 3) / 4, 256, 0, stream>>>(pexp, fsb, src, off, bias, out);
}

// Round 11
// 105.927 us; speedup vs baseline: 1.6737x; 1.0681x over previous
//
#include <hip/hip_runtime.h>
#include <math.h>

#define N_NODES 50000
#define D_IN    128
#define E_EDGES 800000
#define H_HEADS 8
#define F_FEAT  32
#define T_TYPES 8
#define HF      256
#define NEG_SLOPE 0.2f
#define HIST_BLOCKS 64
#define GEMM_BLOCKS 391          // NGROUPS = 782 = 2*391, perfectly balanced
#define OFF_BLOCKS  196          // ceil(50001/256)
#define K1_HIST_BASE GEMM_BLOCKS
#define K1_OFF_BASE  (GEMM_BLOCKS + HIST_BLOCKS)
#define K1_TAB       (GEMM_BLOCKS + HIST_BLOCKS + OFF_BLOCKS)
#define K1_GRID      (K1_TAB + 1)
#define NGROUPS      ((N_NODES + 63) / 64)

using short8 = __attribute__((__ext_vector_type__(8))) short;
using f32x4  = __attribute__((__ext_vector_type__(4))) float;

__device__ inline float bf2f(unsigned short u) {
    union { unsigned int i; float f; } v; v.i = ((unsigned int)u) << 16; return v.f;
}
__device__ inline unsigned short f2bf(float f) {
    unsigned int x = __float_as_uint(f);
    unsigned int r = (x + 0x7fffu + ((x >> 16) & 1u)) >> 16;
    return (unsigned short)r;
}
__device__ inline unsigned int pk2bf(float a, float b) {
    return (unsigned int)f2bf(a) | ((unsigned int)f2bf(b) << 16);
}

// ---------------------------------------------------------------------------
// Kernel 1 (fused, 4 roles): [0,391) MFMA node transform (2 node-groups each);
// [391,455) histogram partials; [455,651) CSR offsets; block 651: M/ttab
// tables. All roles mutually independent.
// ---------------------------------------------------------------------------
__global__ __launch_bounds__(256) void prep_kernel(const float* __restrict__ feat,
                                                   const float* __restrict__ W,
                                                   const float* __restrict__ attn_l,
                                                   const float* __restrict__ attn_r,
                                                   const int*   __restrict__ etype,
                                                   const int*   __restrict__ dst,
                                                   const float* __restrict__ attn_e,
                                                   const float* __restrict__ W_e,
                                                   const float* __restrict__ attn_et,
                                                   const float* __restrict__ W_et,
                                                   const float* __restrict__ type_emb,
                                                   unsigned short* __restrict__ fsb,
                                                   float* __restrict__ el,
                                                   float* __restrict__ er,
                                                   int* __restrict__ partials,
                                                   int* __restrict__ off,
                                                   float* __restrict__ M,
                                                   float* __restrict__ ttab) {
    __shared__ unsigned short Wl[HF * D_IN];   // 64 KB bf16, swizzled
    __shared__ int sw[4][8];
    __shared__ float q[8][32];
    const int t = threadIdx.x;

    if (blockIdx.x == K1_TAB) {                // ---- tables part (M, ttab) ----
        {   // q[h][f2], thread = h*32+f2, coalesced W_et reads
            int h = t >> 5, f2 = t & 31;
            float s = 0.f;
#pragma unroll 8
            for (int f = 0; f < F_FEAT; ++f)
                s += attn_et[h * 32 + f] * W_et[(h * 32 + f) * 32 + f2];
            q[h][f2] = s;
        }
        __syncthreads();
        if (t < 64) {
            int h = t >> 3, j = t & 7;
            float m = 0.f;
#pragma unroll 8
            for (int f = 0; f < F_FEAT; ++f)
                m += attn_e[h * 32 + f] * W_e[(h * 32 + f) * 8 + j];
            M[h * 8 + j] = m;
            float tt = 0.f;
#pragma unroll 8
            for (int f2 = 0; f2 < F_FEAT; ++f2)
                tt += type_emb[j * 32 + f2] * q[h][f2];
            ttab[j * 8 + h] = tt;   // [type][head]
        }
        return;
    }
    if (blockIdx.x >= K1_OFF_BASE) {           // ---- CSR offsets part ----
        int n = (blockIdx.x - K1_OFF_BASE) * 256 + t;
        if (n > N_NODES) return;
        int lo = 0, hi = E_EDGES;
        while (lo < hi) {
            int mid = (lo + hi) >> 1;
            if (dst[mid] < n) lo = mid + 1; else hi = mid;
        }
        off[n] = lo;
        return;
    }
    if (blockIdx.x >= K1_HIST_BASE) {          // ---- histogram part ----
        const int hb = blockIdx.x - K1_HIST_BASE;
        int c[8] = {0,0,0,0,0,0,0,0};
        const int stride = HIST_BLOCKS * 256;
        for (int e = hb * 256 + t; e < E_EDGES; e += stride) {
            int ty = etype[e];
#pragma unroll
            for (int k = 0; k < 8; ++k) c[k] += (ty == k) ? 1 : 0;
        }
#pragma unroll
        for (int k = 0; k < 8; ++k) {
            c[k] += __shfl_xor(c[k], 1);  c[k] += __shfl_xor(c[k], 2);
            c[k] += __shfl_xor(c[k], 4);  c[k] += __shfl_xor(c[k], 8);
            c[k] += __shfl_xor(c[k], 16); c[k] += __shfl_xor(c[k], 32);
        }
        const int wv = t >> 6, l = t & 63;
        if (l == 0) {
#pragma unroll
            for (int k = 0; k < 8; ++k) sw[wv][k] = c[k];
        }
        __syncthreads();
        if (t < 8) partials[hb * 8 + t] = sw[0][t] + sw[1][t] + sw[2][t] + sw[3][t];
        return;
    }

    // ---- MFMA node-transform part (exactly 2 node groups per block) ----
    for (int i = 0; i < 16; ++i) {
        int slot = i * 256 + t;
        int n = slot >> 4, k16 = slot & 15;
        const float* wp = W + (size_t)n * D_IN + k16 * 8;
        float4 w0 = *(const float4*)wp;
        float4 w1 = *(const float4*)(wp + 4);
        union { unsigned int u[4]; short8 s; } ua;
        ua.u[0] = pk2bf(w0.x, w0.y); ua.u[1] = pk2bf(w0.z, w0.w);
        ua.u[2] = pk2bf(w1.x, w1.y); ua.u[3] = pk2bf(w1.z, w1.w);
        int idx = n * D_IN + ((k16 * 8) ^ ((n & 7) << 3));
        *(short8*)&Wl[idx] = ua.s;
    }
    __syncthreads();

    const int wid = t >> 6, l = t & 63;
    const int r16 = l & 15, kq = l >> 4;
    float alv0[8], alv1[8], arv0[8], arv1[8];
#pragma unroll
    for (int h = 0; h < 8; ++h) {
        alv0[h] = attn_l[h * 32 + r16];  alv1[h] = attn_l[h * 32 + 16 + r16];
        arv0[h] = attn_r[h * 32 + r16];  arv1[h] = attn_r[h * 32 + 16 + r16];
    }

    for (int grp = blockIdx.x; grp < NGROUPS; grp += GEMM_BLOCKS) {
        const int node0 = grp * 64 + wid * 16;
        int arow = node0 + r16;
        if (arow >= N_NODES) arow = N_NODES - 1;   // clamp; stores guarded
        const float* fp = feat + (size_t)arow * D_IN + kq * 8;

        f32x4 acc[16];
#pragma unroll
        for (int i = 0; i < 16; ++i) acc[i] = (f32x4){0.f, 0.f, 0.f, 0.f};

#pragma unroll
        for (int kc = 0; kc < 4; ++kc) {
            float4 a0 = *(const float4*)(fp + kc * 32);
            float4 a1 = *(const float4*)(fp + kc * 32 + 4);
            union { unsigned int u[4]; short8 s; } ua;
            ua.u[0] = pk2bf(a0.x, a0.y); ua.u[1] = pk2bf(a0.z, a0.w);
            ua.u[2] = pk2bf(a1.x, a1.y); ua.u[3] = pk2bf(a1.z, a1.w);
            short8 af = ua.s;
#pragma unroll
            for (int nsub = 0; nsub < 16; ++nsub) {
                int n = nsub * 16 + r16;
                int idx = n * D_IN + ((kc * 32 + kq * 8) ^ ((n & 7) << 3));
                short8 bf = *(short8*)&Wl[idx];
                acc[nsub] = __builtin_amdgcn_mfma_f32_16x16x32_bf16(af, bf, acc[nsub], 0, 0, 0);
            }
        }

        const int nodeb = node0 + kq * 4;
#pragma unroll
        for (int h = 0; h < 8; ++h) {
            float ev[4], rv[4];
#pragma unroll
            for (int g = 0; g < 4; ++g) {
                ev[g] = acc[2 * h][g] * alv0[h] + acc[2 * h + 1][g] * alv1[h];
                rv[g] = acc[2 * h][g] * arv0[h] + acc[2 * h + 1][g] * arv1[h];
            }
#pragma unroll
            for (int g = 0; g < 4; ++g) {
                ev[g] += __shfl_xor(ev[g], 1); ev[g] += __shfl_xor(ev[g], 2);
                ev[g] += __shfl_xor(ev[g], 4); ev[g] += __shfl_xor(ev[g], 8);
                rv[g] += __shfl_xor(rv[g], 1); rv[g] += __shfl_xor(rv[g], 2);
                rv[g] += __shfl_xor(rv[g], 4); rv[g] += __shfl_xor(rv[g], 8);
            }
            if (r16 == 0) {
#pragma unroll
                for (int g = 0; g < 4; ++g) {
                    int nd = nodeb + g;
                    if (nd < N_NODES) {
                        el[nd * 8 + h] = ev[g];
                        er[nd * 8 + h] = rv[g];
                    }
                }
            }
        }
#pragma unroll
        for (int nsub = 0; nsub < 16; ++nsub) {
            int col = nsub * 16 + r16;
#pragma unroll
            for (int g = 0; g < 4; ++g) {
                int nd = nodeb + g;
                if (nd < N_NODES) fsb[(size_t)nd * HF + col] = f2bf(acc[nsub][g]);
            }
        }
    }
}

// ---------------------------------------------------------------------------
// Kernel 2: per-edge p = exp(leakyrelu(w*(el+er+escore+tscore))), bf16 out.
//   w[t] reduced per-block from the 64x8 partials (2 KB, L2-broadcast).
// ---------------------------------------------------------------------------
__global__ __launch_bounds__(256) void edge_kernel(const float* __restrict__ ee,
        const int* __restrict__ src, const int* __restrict__ dst,
        const int* __restrict__ etype, const float* __restrict__ el,
        const float* __restrict__ er, const float* __restrict__ M,
        const float* __restrict__ ttab, const int* __restrict__ partials,
        unsigned short* __restrict__ pexp) {
    __shared__ float sM[64], sT[64], sw[8];
    int t = threadIdx.x;
    if (t < 64) {
        sM[t] = M[t]; sT[t] = ttab[t];
        // counts reduce: bin j = t&7, base block b = t>>3, stride 8
        int j = t & 7, b = t >> 3;
        int c = 0;
#pragma unroll 8
        for (int i = 0; i < HIST_BLOCKS / 8; ++i)
            c += partials[(b + 8 * i) * 8 + j];
        c += __shfl_xor(c, 8); c += __shfl_xor(c, 16); c += __shfl_xor(c, 32);
        if (t < 8) {
            if (c < 1) c = 1;
            sw[t] = (float)E_EDGES / (8.0f * (float)c);
        }
    }
    __syncthreads();
    int e = blockIdx.x * 256 + t;
    if (e >= E_EDGES) return;
    int s = src[e], d = dst[e], ty = etype[e];
    float4 e0 = *(const float4*)&ee[(size_t)e * 8];
    float4 e1 = *(const float4*)&ee[(size_t)e * 8 + 4];
    float4 l0 = *(const float4*)&el[s * 8];
    float4 l1 = *(const float4*)&el[s * 8 + 4];
    float4 r0 = *(const float4*)&er[d * 8];
    float4 r1 = *(const float4*)&er[d * 8 + 4];
    float wt = sw[ty];
    float lv[8] = {l0.x,l0.y,l0.z,l0.w,l1.x,l1.y,l1.z,l1.w};
    float rv[8] = {r0.x,r0.y,r0.z,r0.w,r1.x,r1.y,r1.z,r1.w};
    unsigned int o[4];
#pragma unroll
    for (int hp = 0; hp < 4; ++hp) {
        float p2[2];
#pragma unroll
        for (int i = 0; i < 2; ++i) {
            int h = hp * 2 + i;
            float sc = lv[h] + rv[h] + sT[ty * 8 + h];
            sc += e0.x*sM[h*8+0] + e0.y*sM[h*8+1] + e0.z*sM[h*8+2] + e0.w*sM[h*8+3]
                + e1.x*sM[h*8+4] + e1.y*sM[h*8+5] + e1.z*sM[h*8+6] + e1.w*sM[h*8+7];
            sc *= wt;
            sc = (sc >= 0.f) ? sc : NEG_SLOPE * sc;
            p2[i] = __expf(sc);
        }
        o[hp] = (unsigned int)f2bf(p2[0]) | ((unsigned int)f2bf(p2[1]) << 16);
    }
    *(uint4*)&pexp[(size_t)e * 8] = make_uint4(o[0], o[1], o[2], o[3]);
}

// ---------------------------------------------------------------------------
// Kernel 3: single-pass softmax-normalized aggregation. One wave per dst node.
//   Coalesced src read (-> shfl) + pexp chunk staged to wave-private LDS;
//   inner loop = named-scalar unroll-4, fs gather the only global load.
// ---------------------------------------------------------------------------
__global__ __launch_bounds__(256) void agg_kernel(const unsigned short* __restrict__ pexp,
        const unsigned short* __restrict__ fsb, const int* __restrict__ src,
        const int* __restrict__ off, const float* __restrict__ bias,
        float* __restrict__ out) {
    __shared__ unsigned short plds[4][64][8];   // wave-private p scratch (4 KB)
    const int wid = threadIdx.x >> 6;
    const int l = threadIdx.x & 63;
    const int n = blockIdx.x * 4 + wid;
    if (n >= N_NODES) return;
    const int beg = off[n], end = off[n + 1];
    const int c0 = 4 * l;
    const int h = l >> 3;
    const float4 b4 = *(const float4*)&bias[c0];
    float* op = &out[(size_t)n * HF + c0];
    if (beg == end) { *(float4*)op = b4; return; }
    const unsigned short* mp = &plds[wid][0][0];
    float a0 = 0.f, a1 = 0.f, a2 = 0.f, a3 = 0.f, z = 0.f;
    for (int base = beg; base < end; base += 64) {
        const int remn = end - base;
        const int rem = remn < 64 ? remn : 64;
        int idx = base + l; if (idx >= end) idx = end - 1;
        const int sl = src[idx];                 // coalesced
        {   // stage this chunk's pexp block (64x8 bf16 = 1KB) into LDS
            const uint4 pv = *(const uint4*)&pexp[(size_t)idx * 8];
            *(uint4*)&plds[wid][l][0] = pv;
        }
        int j = 0;
        for (; j + 4 <= rem; j += 4) {
            const int s0 = __shfl(sl, j),     s1 = __shfl(sl, j + 1);
            const int s2 = __shfl(sl, j + 2), s3 = __shfl(sl, j + 3);
            const float p0 = bf2f(mp[(j    ) * 8 + h]);
            const float p1 = bf2f(mp[(j + 1) * 8 + h]);
            const float p2 = bf2f(mp[(j + 2) * 8 + h]);
            const float p3 = bf2f(mp[(j + 3) * 8 + h]);
            const ushort4 f0 = *(const ushort4*)&fsb[(size_t)s0 * HF + c0];
            const ushort4 f1 = *(const ushort4*)&fsb[(size_t)s1 * HF + c0];
            const ushort4 f2 = *(const ushort4*)&fsb[(size_t)s2 * HF + c0];
            const ushort4 f3 = *(const ushort4*)&fsb[(size_t)s3 * HF + c0];
            a0 += p0 * bf2f(f0.x); a1 += p0 * bf2f(f0.y);
            a2 += p0 * bf2f(f0.z); a3 += p0 * bf2f(f0.w); z += p0;
            a0 += p1 * bf2f(f1.x); a1 += p1 * bf2f(f1.y);
            a2 += p1 * bf2f(f1.z); a3 += p1 * bf2f(f1.w); z += p1;
            a0 += p2 * bf2f(f2.x); a1 += p2 * bf2f(f2.y);
            a2 += p2 * bf2f(f2.z); a3 += p2 * bf2f(f2.w); z += p2;
            a0 += p3 * bf2f(f3.x); a1 += p3 * bf2f(f3.y);
            a2 += p3 * bf2f(f3.z); a3 += p3 * bf2f(f3.w); z += p3;
        }
        for (; j < rem; ++j) {
            const int s0 = __shfl(sl, j);
            const float p0 = bf2f(mp[j * 8 + h]);
            const ushort4 f0 = *(const ushort4*)&fsb[(size_t)s0 * HF + c0];
            a0 += p0 * bf2f(f0.x); a1 += p0 * bf2f(f0.y);
            a2 += p0 * bf2f(f0.z); a3 += p0 * bf2f(f0.w); z += p0;
        }
    }
    const float rz = 1.f / z;
    *(float4*)op = make_float4(a0 * rz + b4.x, a1 * rz + b4.y,
                               a2 * rz + b4.z, a3 * rz + b4.w);
}

// ---------------------------------------------------------------------------
extern "C" void kernel_launch(void* const* d_in, const int* in_sizes, int n_in,
                              void* d_out, int out_size, void* d_ws, size_t ws_size,
                              hipStream_t stream) {
    const float* feat     = (const float*)d_in[0];
    const float* ee       = (const float*)d_in[1];
    const int*   src      = (const int*)d_in[2];
    const int*   dst      = (const int*)d_in[3];
    const int*   etype    = (const int*)d_in[4];
    const float* W_src    = (const float*)d_in[5];
    const float* attn_l   = (const float*)d_in[6];
    const float* attn_r   = (const float*)d_in[7];
    const float* attn_e   = (const float*)d_in[8];
    const float* W_e      = (const float*)d_in[9];
    const float* type_emb = (const float*)d_in[10];
    const float* W_et     = (const float*)d_in[11];
    const float* attn_et  = (const float*)d_in[12];
    const float* bias     = (const float*)d_in[13];
    float* out = (float*)d_out;

    char* ws = (char*)d_ws;
    size_t o = 0;
    auto alloc = [&](size_t bytes) -> void* {
        void* p = ws + o;
        o = (o + bytes + 255) & ~(size_t)255;
        return p;
    };
    unsigned short* fsb  = (unsigned short*)alloc((size_t)N_NODES * HF * 2); // 25.6 MB
    unsigned short* pexp = (unsigned short*)alloc((size_t)E_EDGES * 8 * 2);  // 12.8 MB
    float* el    = (float*)alloc((size_t)N_NODES * 8 * 4);
    float* er    = (float*)alloc((size_t)N_NODES * 8 * 4);
    int*   off   = (int*)alloc((size_t)(N_NODES + 1) * 4);
    int*   partials = (int*)alloc((size_t)HIST_BLOCKS * 8 * 4);
    float* M     = (float*)alloc(64 * 4);
    float* ttab  = (float*)alloc(64 * 4);

    prep_kernel<<<K1_GRID, 256, 0, stream>>>(feat, W_src, attn_l, attn_r,
                                             etype, dst, attn_e, W_e, attn_et,
                                             W_et, type_emb, fsb, el, er,
                                             partials, off, M, ttab);
    edge_kernel<<<(E_EDGES + 255) / 256, 256, 0, stream>>>(
        ee, src, dst, etype, el, er, M, ttab, partials, pexp);
    agg_kernel<<<(N_NODES + 3) / 4, 256, 0, stream>>>(pexp, fsb, src, off, bias, out);
}